// Round 8
// baseline (256.165 us; speedup 1.0000x reference)
//
#include <hip/hip_runtime.h>

#define E_ 131072

typedef _Float16 half8 __attribute__((ext_vector_type(8)));
typedef float f32x4 __attribute__((ext_vector_type(4)));

__device__ __forceinline__ float gelu_f(float x) {
    return 0.5f * x * (1.0f + erff(x * 0.70710678118654752f));
}

#define TWOPI_64 (6.2831853071795864769f / 64.0f)

__device__ __forceinline__ void block_reduce2(float& s, float& s2, float* red) {
    #pragma unroll
    for (int off = 32; off > 0; off >>= 1) {
        s  += __shfl_down(s, off, 64);
        s2 += __shfl_down(s2, off, 64);
    }
    int lane = threadIdx.x & 63, wv = threadIdx.x >> 6;
    __syncthreads();
    if (lane == 0) { red[wv] = s; red[wv + 4] = s2; }
    __syncthreads();
    s  = red[0] + red[1] + red[2] + red[3];
    s2 = red[4] + red[5] + red[6] + red[7];
}

// ---- GNO 64-edge chunk body (verified R6 code path) ----
__device__ __forceinline__ void gno_body(int e0, float* sbufF, float* sB2, int* ssrc, int* sdst,
                                         const float* __restrict__ ea,
                                         const float* __restrict__ kw1, const float* __restrict__ kb1,
                                         const float* __restrict__ kb2,
                                         const _Float16* __restrict__ whi, const _Float16* __restrict__ wlo,
                                         const float* __restrict__ xn, const int* __restrict__ ei,
                                         float* __restrict__ agg) {
    _Float16* sxTh = (_Float16*)sbufF;
    int t = threadIdx.x;
    int lane = t & 63, wv = t >> 6, quad = lane >> 4, l15 = lane & 15;
    int eg = wv >> 1, t2 = wv & 1;

    if (t < 64) ssrc[t] = ei[e0 + t];
    else if (t < 128) sdst[t - 64] = ei[E_ + e0 + t - 64];
    for (int f = t; f < 1024; f += 256) sB2[f] = kb2[f];
    // phase 1: h = gelu(edge_attr @ kw1 + kb1) (f32, stride 68)
    {
        int r = t >> 2, k0 = (t & 3) * 16;
        const float* ep = ea + (e0 + r) * 6;
        float e6[6];
        #pragma unroll
        for (int d = 0; d < 6; ++d) e6[d] = ep[d];
        #pragma unroll
        for (int kk = 0; kk < 16; ++kk) {
            int k = k0 + kk;
            float acc = kb1[k];
            #pragma unroll
            for (int d = 0; d < 6; ++d) acc += e6[d] * kw1[d * 64 + k];
            sbufF[r * 68 + k] = gelu_f(acc);
        }
    }
    __syncthreads();
    // phase 2: A fragments (hi/lo)
    half8 ahi[2][2], alo[2][2];
    #pragma unroll
    for (int et = 0; et < 2; ++et) {
        #pragma unroll
        for (int kh = 0; kh < 2; ++kh) {
            const float* hp = sbufF + (eg * 32 + et * 16 + l15) * 68 + kh * 32 + quad * 8;
            float4 h0 = *(const float4*)hp;
            float4 h1 = *(const float4*)(hp + 4);
            float hv[8] = {h0.x, h0.y, h0.z, h0.w, h1.x, h1.y, h1.z, h1.w};
            half8 hh, hl;
            #pragma unroll
            for (int j = 0; j < 8; ++j) {
                _Float16 hi = (_Float16)hv[j];
                hh[j] = hi;
                hl[j] = (_Float16)(hv[j] - (float)hi);
            }
            ahi[et][kh] = hh;
            alo[et][kh] = hl;
        }
    }
    __syncthreads();
    // phase 3: gather x rows, f16, fragment-permuted
    {
        int b = t & 3, r = t >> 2;
        int s = ssrc[r];
        int pe = (r >> 5) * 32 + ((r >> 2) & 3) * 8 + ((r >> 4) & 1) * 4 + (r & 3);
        const float4* xp = (const float4*)(xn + (b * 4096 + s) * 32);
        _Float16* dp = sxTh + b * 2312 + pe;
        #pragma unroll
        for (int q = 0; q < 8; ++q) {
            float4 v = xp[q];
            dp[(q * 4 + 0) * 72] = (_Float16)v.x;
            dp[(q * 4 + 1) * 72] = (_Float16)v.y;
            dp[(q * 4 + 2) * 72] = (_Float16)v.z;
            dp[(q * 4 + 3) * 72] = (_Float16)v.w;
        }
    }
    __syncthreads();
    float msg[4][2][4];
    #pragma unroll
    for (int b = 0; b < 4; ++b)
        #pragma unroll
        for (int et = 0; et < 2; ++et)
            #pragma unroll
            for (int r = 0; r < 4; ++r) msg[b][et][r] = 0.f;

    for (int i = 0; i < 32; ++i) {
        float b2v = sB2[i * 32 + t2 * 16 + l15];
        int f0 = (i * 4 + t2 * 2) * 512 + lane * 8;
        half8 bhi0 = *(const half8*)(whi + f0);
        half8 bhi1 = *(const half8*)(whi + f0 + 512);
        half8 blo0 = *(const half8*)(wlo + f0);
        half8 blo1 = *(const half8*)(wlo + f0 + 512);
        f32x4 acc[2];
        #pragma unroll
        for (int et = 0; et < 2; ++et) {
            f32x4 ac = {b2v, b2v, b2v, b2v};
            ac = __builtin_amdgcn_mfma_f32_16x16x32_f16(ahi[et][0], bhi0, ac, 0, 0, 0);
            ac = __builtin_amdgcn_mfma_f32_16x16x32_f16(ahi[et][1], bhi1, ac, 0, 0, 0);
            ac = __builtin_amdgcn_mfma_f32_16x16x32_f16(ahi[et][0], blo0, ac, 0, 0, 0);
            ac = __builtin_amdgcn_mfma_f32_16x16x32_f16(ahi[et][1], blo1, ac, 0, 0, 0);
            ac = __builtin_amdgcn_mfma_f32_16x16x32_f16(alo[et][0], bhi0, ac, 0, 0, 0);
            ac = __builtin_amdgcn_mfma_f32_16x16x32_f16(alo[et][1], bhi1, ac, 0, 0, 0);
            acc[et] = ac;
        }
        #pragma unroll
        for (int b = 0; b < 4; ++b) {
            const half8 xv = *(const half8*)(sxTh + b * 2312 + i * 72 + eg * 32 + quad * 8);
            #pragma unroll
            for (int et = 0; et < 2; ++et) {
                msg[b][et][0] += (float)xv[et * 4 + 0] * acc[et][0];
                msg[b][et][1] += (float)xv[et * 4 + 1] * acc[et][1];
                msg[b][et][2] += (float)xv[et * 4 + 2] * acc[et][2];
                msg[b][et][3] += (float)xv[et * 4 + 3] * acc[et][3];
            }
        }
    }
    int o = t2 * 16 + l15;
    #pragma unroll
    for (int et = 0; et < 2; ++et) {
        #pragma unroll
        for (int r = 0; r < 4; ++r) {
            int row = eg * 32 + et * 16 + quad * 4 + r;
            int d = sdst[row];
            #pragma unroll
            for (int b = 0; b < 4; ++b) {
                atomicAdd(&agg[(b * 4096 + d) * 32 + o], msg[b][et][r]);
            }
        }
    }
}

// ---------------- fused: InstanceNorm + DFT stage1 + agg-zero | w2 repack ----------------
__global__ __launch_bounds__(256, 4) void k_pre(const float* __restrict__ nodes,
                                                const float* __restrict__ w2,
                                                float* __restrict__ xn,
                                                float* __restrict__ agg,
                                                float* __restrict__ Gre, float* __restrict__ Gim,
                                                _Float16* __restrict__ whi, _Float16* __restrict__ wlo) {
    int t = threadIdx.x;
    if (blockIdx.x >= 256) {
        int g0 = (blockIdx.x - 256) * 512 + t;
        #pragma unroll 1
        for (int rep = 0; rep < 2; ++rep) {
            int g = g0 + rep * 256;
            int j = g & 7, l = (g >> 3) & 63, fid = g >> 9;
            int i = fid >> 2, t2 = (fid >> 1) & 1, kh = fid & 1;
            int quad = l >> 4, l15 = l & 15;
            int k = kh * 32 + quad * 8 + j;
            int n = i * 32 + t2 * 16 + l15;
            float v = w2[k * 1024 + n];
            _Float16 hi = (_Float16)v;
            whi[g] = hi;
            wlo[g] = (_Float16)(v - (float)hi);
        }
        return;
    }
    int bh = blockIdx.x;
    __shared__ float sx[2048];
    __shared__ float tc[64], ts[64];
    __shared__ float red[8];
    const float4* src = (const float4*)(nodes + bh * 2048);
    float4* dst = (float4*)(xn + bh * 2048);
    float4* az = (float4*)(agg + bh * 2048);
    if (t < 64) { float a = TWOPI_64 * t; tc[t] = cosf(a); ts[t] = sinf(a); }
    float4 v0 = src[t * 2], v1 = src[t * 2 + 1];
    float s  = v0.x + v0.y + v0.z + v0.w + v1.x + v1.y + v1.z + v1.w;
    float s2 = v0.x*v0.x + v0.y*v0.y + v0.z*v0.z + v0.w*v0.w
             + v1.x*v1.x + v1.y*v1.y + v1.z*v1.z + v1.w*v1.w;
    block_reduce2(s, s2, red);
    float mean = s * (1.0f / 2048.0f);
    float var  = s2 * (1.0f / 2048.0f) - mean * mean;
    float sc = rsqrtf(var + 1e-5f);
    v0.x = (v0.x - mean) * sc; v0.y = (v0.y - mean) * sc;
    v0.z = (v0.z - mean) * sc; v0.w = (v0.w - mean) * sc;
    v1.x = (v1.x - mean) * sc; v1.y = (v1.y - mean) * sc;
    v1.z = (v1.z - mean) * sc; v1.w = (v1.w - mean) * sc;
    dst[t * 2] = v0; dst[t * 2 + 1] = v1;
    float4 z = {0.f, 0.f, 0.f, 0.f};
    az[t * 2] = z; az[t * 2 + 1] = z;
    ((float4*)sx)[t * 2] = v0;
    ((float4*)sx)[t * 2 + 1] = v1;
    __syncthreads();
    #pragma unroll 1
    for (int rep = 0; rep < 2; ++rep) {
        int oi = rep * 256 + t;
        int ky = oi >> 5, i = oi & 31;
        float re = 0.f, im = 0.f;
        #pragma unroll 8
        for (int w = 0; w < 64; ++w) {
            float v = sx[w * 32 + i];
            int m = (ky * w) & 63;
            re += v * tc[m];
            im -= v * ts[m];
        }
        Gre[bh * 512 + oi] = re;
        Gim[bh * 512 + oi] = im;
    }
}

// ---------------- L2: blocks 0..127 = fxy; blocks 128..1535 = GNO chunks 0..1407 ----------------
__global__ __launch_bounds__(256, 4) void k_g1(
        const float* __restrict__ Gre, const float* __restrict__ Gim,
        const float* __restrict__ w1re, const float* __restrict__ w1im,
        const float* __restrict__ w2re, const float* __restrict__ w2im,
        float* __restrict__ Yr, float* __restrict__ Yi,
        const float* __restrict__ ea,
        const float* __restrict__ kw1, const float* __restrict__ kb1,
        const float* __restrict__ kb2,
        const _Float16* __restrict__ whi, const _Float16* __restrict__ wlo,
        const float* __restrict__ xn,
        const int* __restrict__ ei,
        float* __restrict__ agg) {
    __shared__ __align__(16) float U[5648];
    __shared__ int ssrc[64], sdst[64];
    int t = threadIdx.x;

    if (blockIdx.x < 128) {
        float* tc  = U;
        float* ts  = U + 64;
        float* sXr = U + 128;
        float* sXi = U + 656;
        int bid = blockIdx.x;
        int b = bid >> 5, kxi = bid & 31;
        int kx = kxi + (kxi < 16 ? 0 : 32);
        int x = kxi & 15;
        const float* wre = (kxi < 16) ? w1re : w2re;
        const float* wim = (kxi < 16) ? w1im : w2im;
        if (t < 64) { float a = TWOPI_64 * t; tc[t] = cosf(a); ts[t] = sinf(a); }
        __syncthreads();
        #pragma unroll 1
        for (int rep = 0; rep < 2; ++rep) {
            int oi = rep * 256 + t;
            int ky = oi >> 5, i = oi & 31;
            float re = 0.f, im = 0.f;
            #pragma unroll 8
            for (int h = 0; h < 64; ++h) {
                int gidx = (b * 64 + h) * 512 + ky * 32 + i;
                float gr = Gre[gidx], gi = Gim[gidx];
                int m = (kx * h) & 63;
                float c = tc[m], sv = ts[m];
                re += gr * c + gi * sv;
                im += gi * c - gr * sv;
            }
            sXr[ky * 33 + i] = re;
            sXi[ky * 33 + i] = im;
        }
        __syncthreads();
        #pragma unroll 1
        for (int rep = 0; rep < 2; ++rep) {
            int oi = rep * 256 + t;
            int ky = oi & 15, o = oi >> 4;
            float re = 0.f, im = 0.f;
            #pragma unroll 4
            for (int i = 0; i < 32; ++i) {
                float xr = sXr[ky * 33 + i], xi = sXi[ky * 33 + i];
                int widx = (i * 32 + o) * 256 + x * 16 + ky;
                float wr = wre[widx], wi = wim[widx];
                re += xr * wr - xi * wi;
                im += xr * wi + xi * wr;
            }
            Yr[bid * 512 + ky * 32 + o] = re;
            Yi[bid * 512 + ky * 32 + o] = im;
        }
        return;
    }
    gno_body((blockIdx.x - 128) * 64, U, U + 4624, ssrc, sdst,
             ea, kw1, kb1, kb2, whi, wlo, xn, ei, agg);
}

// ---------------- L3: blocks 0..255 = zx1 (Z+irfft+IN+MLP -> osum); blocks 256..895 = GNO chunks 1408..2047 ----------------
__global__ __launch_bounds__(256, 4) void k_g2(
        const float* __restrict__ Yr, const float* __restrict__ Yi,
        const float* __restrict__ mw1, const float* __restrict__ mb1,
        const float* __restrict__ mw2, const float* __restrict__ mb2,
        float* __restrict__ osum,
        const float* __restrict__ ea,
        const float* __restrict__ kw1, const float* __restrict__ kb1,
        const float* __restrict__ kb2,
        const _Float16* __restrict__ whi, const _Float16* __restrict__ wlo,
        const float* __restrict__ xn,
        const int* __restrict__ ei,
        float* __restrict__ agg) {
    __shared__ __align__(16) float U[11584];
    __shared__ int ssrc[64], sdst[64];
    int t = threadIdx.x;

    if (blockIdx.x < 256) {
        int bh = blockIdx.x;
        int b = bh >> 6, h = bh & 63;
        float* tc  = U;
        float* ts  = U + 64;
        float* red = U + 128;
        float* sZr = U + 136;    // 16*33
        float* sZi = U + 664;    // 16*33
        float* sP  = U + 1192;   // 64*33
        float* sW1 = U + 3304;   // 2048
        float* sW2 = U + 5352;   // 2048
        float* sH  = U + 7400;   // 64*65
        if (t < 64) { float a = TWOPI_64 * t; tc[t] = cosf(a); ts[t] = sinf(a); }
        for (int f = t; f < 2048; f += 256) { sW1[f] = mw1[f]; sW2[f] = mw2[f]; }
        __syncthreads();
        // Z stage
        #pragma unroll 1
        for (int rep = 0; rep < 2; ++rep) {
            int oi = rep * 256 + t;
            int ky = oi >> 5, o = oi & 31;
            float re = 0.f, im = 0.f;
            #pragma unroll 4
            for (int kxi = 0; kxi < 32; ++kxi) {
                int kx = kxi + (kxi < 16 ? 0 : 32);
                int m = (kx * h) & 63;
                float c = tc[m], sv = ts[m];
                int yidx = (b * 32 + kxi) * 512 + ky * 32 + o;
                float yr = Yr[yidx], yi = Yi[yidx];
                re += yr * c - yi * sv;
                im += yr * sv + yi * c;
            }
            sZr[ky * 33 + o] = re;
            sZi[ky * 33 + o] = im;
        }
        __syncthreads();
        // irfft + IN -> sP
        float s = 0.f, s2 = 0.f;
        #pragma unroll 1
        for (int rep = 0; rep < 8; ++rep) {
            int idx = rep * 256 + t;
            int w = idx >> 5, o = idx & 31;
            float acc = sZr[o];  // ky=0: real part only (irfft drops imag of DC bin)
            #pragma unroll
            for (int ky = 1; ky < 16; ++ky) {
                int m = (ky * w) & 63;
                acc += 2.0f * (sZr[ky * 33 + o] * tc[m] - sZi[ky * 33 + o] * ts[m]);
            }
            acc *= (1.0f / 4096.0f);
            sP[w * 33 + o] = acc;
            s += acc; s2 += acc * acc;
        }
        block_reduce2(s, s2, red);
        float mean = s * (1.0f / 2048.0f);
        float sc = rsqrtf(s2 * (1.0f / 2048.0f) - mean * mean + 1e-5f);
        #pragma unroll 1
        for (int rep = 0; rep < 8; ++rep) {
            int idx = rep * 256 + t;
            int w = idx >> 5, o = idx & 31;
            sP[w * 33 + o] = (sP[w * 33 + o] - mean) * sc;
        }
        __syncthreads();
        // x1 hidden
        #pragma unroll 1
        for (int rep = 0; rep < 16; ++rep) {
            int idx = rep * 256 + t;
            int w = idx >> 6, k = idx & 63;
            float acc = mb1[k];
            #pragma unroll 4
            for (int c = 0; c < 32; ++c) acc += sP[w * 33 + c] * sW1[c * 64 + k];
            sH[w * 65 + k] = gelu_f(acc);
        }
        __syncthreads();
        // x1 out -> osum
        #pragma unroll 1
        for (int rep = 0; rep < 8; ++rep) {
            int idx = rep * 256 + t;
            int w = idx >> 5, o = idx & 31;
            float acc = mb2[o];
            #pragma unroll 4
            for (int k = 0; k < 64; ++k) acc += sH[w * 65 + k] * sW2[k * 32 + o];
            osum[bh * 2048 + idx] = acc;
        }
        return;
    }
    gno_body((1408 + blockIdx.x - 256) * 64, U, U + 4624, ssrc, sdst,
             ea, kw1, kb1, kb2, whi, wlo, xn, ei, agg);
}

// ---------------- L4: x2 (MLP+IN) fused with final: out = gelu(osum + agg + x2 + xn@root + gbias) ----------------
__global__ __launch_bounds__(256, 2) void k_final2(const float* __restrict__ osum, const float* __restrict__ agg,
                                                   const float* __restrict__ xn,
                                                   const float* __restrict__ ww1, const float* __restrict__ wb1,
                                                   const float* __restrict__ ww2, const float* __restrict__ wb2,
                                                   const float* __restrict__ root, const float* __restrict__ gbias,
                                                   float* __restrict__ out) {
    int bh = blockIdx.x;
    int t = threadIdx.x;
    __shared__ float red[8];
    __shared__ float sX[2112];   // xn row (kept for root GEMM)
    __shared__ float sH[4160];
    __shared__ float sW1[2048], sW2[2048];
    __shared__ float sR[1024];
    __shared__ float sP[2112];   // unnormalized x2
    for (int f = t; f < 2048; f += 256) {
        sW1[f] = ww1[f]; sW2[f] = ww2[f];
        sX[(f >> 5) * 33 + (f & 31)] = xn[bh * 2048 + f];
    }
    for (int f = t; f < 1024; f += 256) sR[f] = root[f];
    __syncthreads();
    // x2 hidden
    #pragma unroll 1
    for (int rep = 0; rep < 16; ++rep) {
        int idx = rep * 256 + t;
        int w = idx >> 6, k = idx & 63;
        float acc = wb1[k];
        #pragma unroll 4
        for (int c = 0; c < 32; ++c) acc += sX[w * 33 + c] * sW1[c * 64 + k];
        sH[w * 65 + k] = gelu_f(acc);
    }
    __syncthreads();
    // x2 out + moments
    float s = 0.f, s2 = 0.f;
    #pragma unroll 1
    for (int rep = 0; rep < 8; ++rep) {
        int idx = rep * 256 + t;
        int w = idx >> 5, o = idx & 31;
        float acc = wb2[o];
        #pragma unroll 4
        for (int k = 0; k < 64; ++k) acc += sH[w * 65 + k] * sW2[k * 32 + o];
        sP[w * 33 + o] = acc;
        s += acc; s2 += acc * acc;
    }
    block_reduce2(s, s2, red);
    float mean = s * (1.0f / 2048.0f);
    float sc = rsqrtf(s2 * (1.0f / 2048.0f) - mean * mean + 1e-5f);
    // final: osum + agg + x2norm + xn@root + gbias, gelu
    #pragma unroll 1
    for (int rep = 0; rep < 8; ++rep) {
        int idx = rep * 256 + t;
        int w = idx >> 5, o = idx & 31;
        float acc = gbias[o] + osum[bh * 2048 + idx] + agg[bh * 2048 + idx]
                  + (sP[w * 33 + o] - mean) * sc;
        #pragma unroll 4
        for (int c = 0; c < 32; ++c) acc += sX[w * 33 + c] * sR[c * 32 + o];
        out[bh * 2048 + idx] = gelu_f(acc);
    }
}

extern "C" void kernel_launch(void* const* d_in, const int* in_sizes, int n_in,
                              void* d_out, int out_size, void* d_ws, size_t ws_size,
                              hipStream_t stream) {
    (void)in_sizes; (void)n_in; (void)out_size; (void)ws_size;
    const float* nodes  = (const float*)d_in[0];
    const int*   eidx   = (const int*)d_in[1];
    const float* eattr  = (const float*)d_in[2];
    const float* w1re   = (const float*)d_in[3];
    const float* w1im   = (const float*)d_in[4];
    const float* w2re   = (const float*)d_in[5];
    const float* w2im   = (const float*)d_in[6];
    const float* mlp_w1 = (const float*)d_in[7];
    const float* mlp_b1 = (const float*)d_in[8];
    const float* mlp_w2 = (const float*)d_in[9];
    const float* mlp_b2 = (const float*)d_in[10];
    const float* wm_w1  = (const float*)d_in[11];
    const float* wm_b1  = (const float*)d_in[12];
    const float* wm_w2  = (const float*)d_in[13];
    const float* wm_b2  = (const float*)d_in[14];
    const float* ker_w1 = (const float*)d_in[15];
    const float* ker_b1 = (const float*)d_in[16];
    const float* ker_w2 = (const float*)d_in[17];
    const float* ker_b2 = (const float*)d_in[18];
    const float* root   = (const float*)d_in[19];
    const float* gbias  = (const float*)d_in[20];
    float* out = (float*)d_out;

    char* ws = (char*)d_ws;
    size_t off = 0;
    auto alloc = [&](size_t bytes) {
        void* p = ws + off;
        off += (bytes + 255) & ~(size_t)255;
        return p;
    };
    float* xn   = (float*)alloc(524288 * 4);
    float* agg  = (float*)alloc(524288 * 4);
    float* osum = (float*)alloc(524288 * 4);
    float* Gre  = (float*)alloc(131072 * 4);
    float* Gim  = (float*)alloc(131072 * 4);
    float* Yr   = (float*)alloc(65536 * 4);
    float* Yi   = (float*)alloc(65536 * 4);
    _Float16* whi = (_Float16*)alloc(65536 * 2);
    _Float16* wlo = (_Float16*)alloc(65536 * 2);

    k_pre<<<384, 256, 0, stream>>>(nodes, ker_w2, xn, agg, Gre, Gim, whi, wlo);
    k_g1<<<1536, 256, 0, stream>>>(Gre, Gim, w1re, w1im, w2re, w2im, Yr, Yi,
                                   eattr, ker_w1, ker_b1, ker_b2, whi, wlo, xn, eidx, agg);
    k_g2<<<896, 256, 0, stream>>>(Yr, Yi, mlp_w1, mlp_b1, mlp_w2, mlp_b2, osum,
                                  eattr, ker_w1, ker_b1, ker_b2, whi, wlo, xn, eidx, agg);
    k_final2<<<256, 256, 0, stream>>>(osum, agg, xn, wm_w1, wm_b1, wm_w2, wm_b2, root, gbias, out);
}

// Round 9
// 254.363 us; speedup vs baseline: 1.0071x; 1.0071x over previous
//
#include <hip/hip_runtime.h>

#define E_ 131072

typedef _Float16 half8 __attribute__((ext_vector_type(8)));
typedef float f32x4 __attribute__((ext_vector_type(4)));

__device__ __forceinline__ float gelu_f(float x) {
    return 0.5f * x * (1.0f + erff(x * 0.70710678118654752f));
}

#define TWOPI_64 (6.2831853071795864769f / 64.0f)

__device__ __forceinline__ void block_reduce2(float& s, float& s2, float* red) {
    #pragma unroll
    for (int off = 32; off > 0; off >>= 1) {
        s  += __shfl_down(s, off, 64);
        s2 += __shfl_down(s2, off, 64);
    }
    int lane = threadIdx.x & 63, wv = threadIdx.x >> 6;
    __syncthreads();
    if (lane == 0) { red[wv] = s; red[wv + 4] = s2; }
    __syncthreads();
    s  = red[0] + red[1] + red[2] + red[3];
    s2 = red[4] + red[5] + red[6] + red[7];
}

// ---- GNO 64-edge chunk body (verified R6/R8 code path, untouched) ----
__device__ __forceinline__ void gno_body(int e0, float* sbufF, float* sB2, int* ssrc, int* sdst,
                                         const float* __restrict__ ea,
                                         const float* __restrict__ kw1, const float* __restrict__ kb1,
                                         const float* __restrict__ kb2,
                                         const _Float16* __restrict__ whi, const _Float16* __restrict__ wlo,
                                         const float* __restrict__ xn, const int* __restrict__ ei,
                                         float* __restrict__ agg) {
    _Float16* sxTh = (_Float16*)sbufF;
    int t = threadIdx.x;
    int lane = t & 63, wv = t >> 6, quad = lane >> 4, l15 = lane & 15;
    int eg = wv >> 1, t2 = wv & 1;

    if (t < 64) ssrc[t] = ei[e0 + t];
    else if (t < 128) sdst[t - 64] = ei[E_ + e0 + t - 64];
    for (int f = t; f < 1024; f += 256) sB2[f] = kb2[f];
    {
        int r = t >> 2, k0 = (t & 3) * 16;
        const float* ep = ea + (e0 + r) * 6;
        float e6[6];
        #pragma unroll
        for (int d = 0; d < 6; ++d) e6[d] = ep[d];
        #pragma unroll
        for (int kk = 0; kk < 16; ++kk) {
            int k = k0 + kk;
            float acc = kb1[k];
            #pragma unroll
            for (int d = 0; d < 6; ++d) acc += e6[d] * kw1[d * 64 + k];
            sbufF[r * 68 + k] = gelu_f(acc);
        }
    }
    __syncthreads();
    half8 ahi[2][2], alo[2][2];
    #pragma unroll
    for (int et = 0; et < 2; ++et) {
        #pragma unroll
        for (int kh = 0; kh < 2; ++kh) {
            const float* hp = sbufF + (eg * 32 + et * 16 + l15) * 68 + kh * 32 + quad * 8;
            float4 h0 = *(const float4*)hp;
            float4 h1 = *(const float4*)(hp + 4);
            float hv[8] = {h0.x, h0.y, h0.z, h0.w, h1.x, h1.y, h1.z, h1.w};
            half8 hh, hl;
            #pragma unroll
            for (int j = 0; j < 8; ++j) {
                _Float16 hi = (_Float16)hv[j];
                hh[j] = hi;
                hl[j] = (_Float16)(hv[j] - (float)hi);
            }
            ahi[et][kh] = hh;
            alo[et][kh] = hl;
        }
    }
    __syncthreads();
    {
        int b = t & 3, r = t >> 2;
        int s = ssrc[r];
        int pe = (r >> 5) * 32 + ((r >> 2) & 3) * 8 + ((r >> 4) & 1) * 4 + (r & 3);
        const float4* xp = (const float4*)(xn + (b * 4096 + s) * 32);
        _Float16* dp = sxTh + b * 2312 + pe;
        #pragma unroll
        for (int q = 0; q < 8; ++q) {
            float4 v = xp[q];
            dp[(q * 4 + 0) * 72] = (_Float16)v.x;
            dp[(q * 4 + 1) * 72] = (_Float16)v.y;
            dp[(q * 4 + 2) * 72] = (_Float16)v.z;
            dp[(q * 4 + 3) * 72] = (_Float16)v.w;
        }
    }
    __syncthreads();
    float msg[4][2][4];
    #pragma unroll
    for (int b = 0; b < 4; ++b)
        #pragma unroll
        for (int et = 0; et < 2; ++et)
            #pragma unroll
            for (int r = 0; r < 4; ++r) msg[b][et][r] = 0.f;

    for (int i = 0; i < 32; ++i) {
        float b2v = sB2[i * 32 + t2 * 16 + l15];
        int f0 = (i * 4 + t2 * 2) * 512 + lane * 8;
        half8 bhi0 = *(const half8*)(whi + f0);
        half8 bhi1 = *(const half8*)(whi + f0 + 512);
        half8 blo0 = *(const half8*)(wlo + f0);
        half8 blo1 = *(const half8*)(wlo + f0 + 512);
        f32x4 acc[2];
        #pragma unroll
        for (int et = 0; et < 2; ++et) {
            f32x4 ac = {b2v, b2v, b2v, b2v};
            ac = __builtin_amdgcn_mfma_f32_16x16x32_f16(ahi[et][0], bhi0, ac, 0, 0, 0);
            ac = __builtin_amdgcn_mfma_f32_16x16x32_f16(ahi[et][1], bhi1, ac, 0, 0, 0);
            ac = __builtin_amdgcn_mfma_f32_16x16x32_f16(ahi[et][0], blo0, ac, 0, 0, 0);
            ac = __builtin_amdgcn_mfma_f32_16x16x32_f16(ahi[et][1], blo1, ac, 0, 0, 0);
            ac = __builtin_amdgcn_mfma_f32_16x16x32_f16(alo[et][0], bhi0, ac, 0, 0, 0);
            ac = __builtin_amdgcn_mfma_f32_16x16x32_f16(alo[et][1], bhi1, ac, 0, 0, 0);
            acc[et] = ac;
        }
        #pragma unroll
        for (int b = 0; b < 4; ++b) {
            const half8 xv = *(const half8*)(sxTh + b * 2312 + i * 72 + eg * 32 + quad * 8);
            #pragma unroll
            for (int et = 0; et < 2; ++et) {
                msg[b][et][0] += (float)xv[et * 4 + 0] * acc[et][0];
                msg[b][et][1] += (float)xv[et * 4 + 1] * acc[et][1];
                msg[b][et][2] += (float)xv[et * 4 + 2] * acc[et][2];
                msg[b][et][3] += (float)xv[et * 4 + 3] * acc[et][3];
            }
        }
    }
    int o = t2 * 16 + l15;
    #pragma unroll
    for (int et = 0; et < 2; ++et) {
        #pragma unroll
        for (int r = 0; r < 4; ++r) {
            int row = eg * 32 + et * 16 + quad * 4 + r;
            int d = sdst[row];
            #pragma unroll
            for (int b = 0; b < 4; ++b) {
                atomicAdd(&agg[(b * 4096 + d) * 32 + o], msg[b][et][r]);
            }
        }
    }
}

// ---------------- L1: IN + DFT1 + agg-zero + x2(MLP+IN)->osum | w2 repack ----------------
__global__ __launch_bounds__(256, 4) void k_pre(const float* __restrict__ nodes,
                                                const float* __restrict__ w2,
                                                const float* __restrict__ ww1, const float* __restrict__ wb1,
                                                const float* __restrict__ ww2, const float* __restrict__ wb2,
                                                float* __restrict__ xn,
                                                float* __restrict__ agg,
                                                float* __restrict__ osum,
                                                float* __restrict__ Gre, float* __restrict__ Gim,
                                                _Float16* __restrict__ whi, _Float16* __restrict__ wlo) {
    int t = threadIdx.x;
    if (blockIdx.x >= 256) {
        int g0 = (blockIdx.x - 256) * 512 + t;
        #pragma unroll 1
        for (int rep = 0; rep < 2; ++rep) {
            int g = g0 + rep * 256;
            int j = g & 7, l = (g >> 3) & 63, fid = g >> 9;
            int i = fid >> 2, t2 = (fid >> 1) & 1, kh = fid & 1;
            int quad = l >> 4, l15 = l & 15;
            int k = kh * 32 + quad * 8 + j;
            int n = i * 32 + t2 * 16 + l15;
            float v = w2[k * 1024 + n];
            _Float16 hi = (_Float16)v;
            whi[g] = hi;
            wlo[g] = (_Float16)(v - (float)hi);
        }
        return;
    }
    int bh = blockIdx.x;
    __shared__ float sx[2112];          // xn plane, padded stride 33
    __shared__ float tc[64], ts[64];
    __shared__ float red[8];
    __shared__ float sW1[2048], sW2[2048];
    __shared__ float sH[4160];          // 64*65
    const float4* src = (const float4*)(nodes + bh * 2048);
    float4* dst = (float4*)(xn + bh * 2048);
    float4* az = (float4*)(agg + bh * 2048);
    if (t < 64) { float a = TWOPI_64 * t; tc[t] = cosf(a); ts[t] = sinf(a); }
    for (int f = t; f < 2048; f += 256) { sW1[f] = ww1[f]; sW2[f] = ww2[f]; }
    float4 v0 = src[t * 2], v1 = src[t * 2 + 1];
    float s  = v0.x + v0.y + v0.z + v0.w + v1.x + v1.y + v1.z + v1.w;
    float s2 = v0.x*v0.x + v0.y*v0.y + v0.z*v0.z + v0.w*v0.w
             + v1.x*v1.x + v1.y*v1.y + v1.z*v1.z + v1.w*v1.w;
    block_reduce2(s, s2, red);
    float mean = s * (1.0f / 2048.0f);
    float var  = s2 * (1.0f / 2048.0f) - mean * mean;
    float sc = rsqrtf(var + 1e-5f);
    v0.x = (v0.x - mean) * sc; v0.y = (v0.y - mean) * sc;
    v0.z = (v0.z - mean) * sc; v0.w = (v0.w - mean) * sc;
    v1.x = (v1.x - mean) * sc; v1.y = (v1.y - mean) * sc;
    v1.z = (v1.z - mean) * sc; v1.w = (v1.w - mean) * sc;
    dst[t * 2] = v0; dst[t * 2 + 1] = v1;
    float4 z = {0.f, 0.f, 0.f, 0.f};
    az[t * 2] = z; az[t * 2 + 1] = z;
    {
        int w = t >> 2, c0 = (t & 3) * 8;
        float* p = sx + w * 33 + c0;
        p[0] = v0.x; p[1] = v0.y; p[2] = v0.z; p[3] = v0.w;
        p[4] = v1.x; p[5] = v1.y; p[6] = v1.z; p[7] = v1.w;
    }
    __syncthreads();
    // DFT stage 1 over w
    #pragma unroll 1
    for (int rep = 0; rep < 2; ++rep) {
        int oi = rep * 256 + t;
        int ky = oi >> 5, i = oi & 31;
        float re = 0.f, im = 0.f;
        #pragma unroll 8
        for (int w = 0; w < 64; ++w) {
            float v = sx[w * 33 + i];
            int m = (ky * w) & 63;
            re += v * tc[m];
            im -= v * ts[m];
        }
        Gre[bh * 512 + oi] = re;
        Gim[bh * 512 + oi] = im;
    }
    __syncthreads();
    // x2 hidden
    #pragma unroll 1
    for (int rep = 0; rep < 16; ++rep) {
        int idx = rep * 256 + t;
        int w = idx >> 6, k = idx & 63;
        float acc = wb1[k];
        #pragma unroll 4
        for (int c = 0; c < 32; ++c) acc += sx[w * 33 + c] * sW1[c * 64 + k];
        sH[w * 65 + k] = gelu_f(acc);
    }
    __syncthreads();    // sW1 free
    // x2 out -> stash in sW1 + moments
    s = 0.f; s2 = 0.f;
    #pragma unroll 1
    for (int rep = 0; rep < 8; ++rep) {
        int idx = rep * 256 + t;
        int w = idx >> 5, o = idx & 31;
        float acc = wb2[o];
        #pragma unroll 4
        for (int k = 0; k < 64; ++k) acc += sH[w * 65 + k] * sW2[k * 32 + o];
        sW1[idx] = acc;
        s += acc; s2 += acc * acc;
    }
    block_reduce2(s, s2, red);
    mean = s * (1.0f / 2048.0f);
    sc = rsqrtf(s2 * (1.0f / 2048.0f) - mean * mean + 1e-5f);
    #pragma unroll 1
    for (int rep = 0; rep < 8; ++rep) {
        int idx = rep * 256 + t;
        osum[bh * 2048 + idx] = (sW1[idx] - mean) * sc;
    }
}

// ---------------- L2: blocks 0..127 = fxy; blocks 128..1279 = GNO chunks 0..1151 ----------------
__global__ __launch_bounds__(256, 4) void k_g1(
        const float* __restrict__ Gre, const float* __restrict__ Gim,
        const float* __restrict__ w1re, const float* __restrict__ w1im,
        const float* __restrict__ w2re, const float* __restrict__ w2im,
        float* __restrict__ Yr, float* __restrict__ Yi,
        const float* __restrict__ ea,
        const float* __restrict__ kw1, const float* __restrict__ kb1,
        const float* __restrict__ kb2,
        const _Float16* __restrict__ whi, const _Float16* __restrict__ wlo,
        const float* __restrict__ xn,
        const int* __restrict__ ei,
        float* __restrict__ agg) {
    __shared__ __align__(16) float U[5648];
    __shared__ int ssrc[64], sdst[64];
    int t = threadIdx.x;

    if (blockIdx.x < 128) {
        float* tc  = U;
        float* ts  = U + 64;
        float* sXr = U + 128;
        float* sXi = U + 656;
        int bid = blockIdx.x;
        int b = bid >> 5, kxi = bid & 31;
        int kx = kxi + (kxi < 16 ? 0 : 32);
        int x = kxi & 15;
        const float* wre = (kxi < 16) ? w1re : w2re;
        const float* wim = (kxi < 16) ? w1im : w2im;
        if (t < 64) { float a = TWOPI_64 * t; tc[t] = cosf(a); ts[t] = sinf(a); }
        __syncthreads();
        #pragma unroll 1
        for (int rep = 0; rep < 2; ++rep) {
            int oi = rep * 256 + t;
            int ky = oi >> 5, i = oi & 31;
            float re = 0.f, im = 0.f;
            #pragma unroll 8
            for (int h = 0; h < 64; ++h) {
                int gidx = (b * 64 + h) * 512 + ky * 32 + i;
                float gr = Gre[gidx], gi = Gim[gidx];
                int m = (kx * h) & 63;
                float c = tc[m], sv = ts[m];
                re += gr * c + gi * sv;
                im += gi * c - gr * sv;
            }
            sXr[ky * 33 + i] = re;
            sXi[ky * 33 + i] = im;
        }
        __syncthreads();
        #pragma unroll 1
        for (int rep = 0; rep < 2; ++rep) {
            int oi = rep * 256 + t;
            int ky = oi & 15, o = oi >> 4;
            float re = 0.f, im = 0.f;
            #pragma unroll 4
            for (int i = 0; i < 32; ++i) {
                float xr = sXr[ky * 33 + i], xi = sXi[ky * 33 + i];
                int widx = (i * 32 + o) * 256 + x * 16 + ky;
                float wr = wre[widx], wi = wim[widx];
                re += xr * wr - xi * wi;
                im += xr * wi + xi * wr;
            }
            Yr[bid * 512 + ky * 32 + o] = re;
            Yi[bid * 512 + ky * 32 + o] = im;
        }
        return;
    }
    gno_body((blockIdx.x - 128) * 64, U, U + 4624, ssrc, sdst,
             ea, kw1, kb1, kb2, whi, wlo, xn, ei, agg);
}

// ---------------- L3: blocks 0..255 = zx1 (osum += x1); blocks 256..1151 = GNO chunks 1152..2047 ----------------
__global__ __launch_bounds__(256, 4) void k_g2(
        const float* __restrict__ Yr, const float* __restrict__ Yi,
        const float* __restrict__ mw1, const float* __restrict__ mb1,
        const float* __restrict__ mw2, const float* __restrict__ mb2,
        float* __restrict__ osum,
        const float* __restrict__ ea,
        const float* __restrict__ kw1, const float* __restrict__ kb1,
        const float* __restrict__ kb2,
        const _Float16* __restrict__ whi, const _Float16* __restrict__ wlo,
        const float* __restrict__ xn,
        const int* __restrict__ ei,
        float* __restrict__ agg) {
    __shared__ __align__(16) float U[11584];
    __shared__ int ssrc[64], sdst[64];
    int t = threadIdx.x;

    if (blockIdx.x < 256) {
        int bh = blockIdx.x;
        int b = bh >> 6, h = bh & 63;
        float* tc  = U;
        float* ts  = U + 64;
        float* red = U + 128;
        float* sZr = U + 136;    // 16*33
        float* sZi = U + 664;    // 16*33
        float* sP  = U + 1192;   // 64*33
        float* sW1 = U + 3304;   // 2048
        float* sW2 = U + 5352;   // 2048
        float* sH  = U + 7400;   // 64*65
        if (t < 64) { float a = TWOPI_64 * t; tc[t] = cosf(a); ts[t] = sinf(a); }
        for (int f = t; f < 2048; f += 256) { sW1[f] = mw1[f]; sW2[f] = mw2[f]; }
        __syncthreads();
        #pragma unroll 1
        for (int rep = 0; rep < 2; ++rep) {
            int oi = rep * 256 + t;
            int ky = oi >> 5, o = oi & 31;
            float re = 0.f, im = 0.f;
            #pragma unroll 4
            for (int kxi = 0; kxi < 32; ++kxi) {
                int kx = kxi + (kxi < 16 ? 0 : 32);
                int m = (kx * h) & 63;
                float c = tc[m], sv = ts[m];
                int yidx = (b * 32 + kxi) * 512 + ky * 32 + o;
                float yr = Yr[yidx], yi = Yi[yidx];
                re += yr * c - yi * sv;
                im += yr * sv + yi * c;
            }
            sZr[ky * 33 + o] = re;
            sZi[ky * 33 + o] = im;
        }
        __syncthreads();
        float s = 0.f, s2 = 0.f;
        #pragma unroll 1
        for (int rep = 0; rep < 8; ++rep) {
            int idx = rep * 256 + t;
            int w = idx >> 5, o = idx & 31;
            float acc = sZr[o];  // ky=0: real part only (irfft drops imag of DC bin)
            #pragma unroll
            for (int ky = 1; ky < 16; ++ky) {
                int m = (ky * w) & 63;
                acc += 2.0f * (sZr[ky * 33 + o] * tc[m] - sZi[ky * 33 + o] * ts[m]);
            }
            acc *= (1.0f / 4096.0f);
            sP[w * 33 + o] = acc;
            s += acc; s2 += acc * acc;
        }
        block_reduce2(s, s2, red);
        float mean = s * (1.0f / 2048.0f);
        float sc = rsqrtf(s2 * (1.0f / 2048.0f) - mean * mean + 1e-5f);
        #pragma unroll 1
        for (int rep = 0; rep < 8; ++rep) {
            int idx = rep * 256 + t;
            int w = idx >> 5, o = idx & 31;
            sP[w * 33 + o] = (sP[w * 33 + o] - mean) * sc;
        }
        __syncthreads();
        #pragma unroll 1
        for (int rep = 0; rep < 16; ++rep) {
            int idx = rep * 256 + t;
            int w = idx >> 6, k = idx & 63;
            float acc = mb1[k];
            #pragma unroll 4
            for (int c = 0; c < 32; ++c) acc += sP[w * 33 + c] * sW1[c * 64 + k];
            sH[w * 65 + k] = gelu_f(acc);
        }
        __syncthreads();
        #pragma unroll 1
        for (int rep = 0; rep < 8; ++rep) {
            int idx = rep * 256 + t;
            int w = idx >> 5, o = idx & 31;
            float acc = mb2[o];
            #pragma unroll 4
            for (int k = 0; k < 64; ++k) acc += sH[w * 65 + k] * sW2[k * 32 + o];
            osum[bh * 2048 + idx] += acc;
        }
        return;
    }
    gno_body((1152 + blockIdx.x - 256) * 64, U, U + 4624, ssrc, sdst,
             ea, kw1, kb1, kb2, whi, wlo, xn, ei, agg);
}

// ---------------- L4: out = gelu(osum + agg + xn@root + gbias), quarter-planes ----------------
__global__ __launch_bounds__(256, 4) void k_final(const float* __restrict__ osum, const float* __restrict__ agg,
                                                  const float* __restrict__ xn, const float* __restrict__ root,
                                                  const float* __restrict__ gbias, float* __restrict__ out) {
    int bh = blockIdx.x >> 2, q = blockIdx.x & 3;
    int base = bh * 2048 + q * 512;
    int t = threadIdx.x;
    __shared__ float sX[16 * 33];
    __shared__ float sR[1024];
    for (int f = t; f < 512; f += 256) sX[(f >> 5) * 33 + (f & 31)] = xn[base + f];
    for (int f = t; f < 1024; f += 256) sR[f] = root[f];
    __syncthreads();
    #pragma unroll 1
    for (int rep = 0; rep < 2; ++rep) {
        int idx = rep * 256 + t;
        int w = idx >> 5, o = idx & 31;
        float acc = gbias[o] + osum[base + idx] + agg[base + idx];
        #pragma unroll 4
        for (int c = 0; c < 32; ++c) acc += sX[w * 33 + c] * sR[c * 32 + o];
        out[base + idx] = gelu_f(acc);
    }
}

extern "C" void kernel_launch(void* const* d_in, const int* in_sizes, int n_in,
                              void* d_out, int out_size, void* d_ws, size_t ws_size,
                              hipStream_t stream) {
    (void)in_sizes; (void)n_in; (void)out_size; (void)ws_size;
    const float* nodes  = (const float*)d_in[0];
    const int*   eidx   = (const int*)d_in[1];
    const float* eattr  = (const float*)d_in[2];
    const float* w1re   = (const float*)d_in[3];
    const float* w1im   = (const float*)d_in[4];
    const float* w2re   = (const float*)d_in[5];
    const float* w2im   = (const float*)d_in[6];
    const float* mlp_w1 = (const float*)d_in[7];
    const float* mlp_b1 = (const float*)d_in[8];
    const float* mlp_w2 = (const float*)d_in[9];
    const float* mlp_b2 = (const float*)d_in[10];
    const float* wm_w1  = (const float*)d_in[11];
    const float* wm_b1  = (const float*)d_in[12];
    const float* wm_w2  = (const float*)d_in[13];
    const float* wm_b2  = (const float*)d_in[14];
    const float* ker_w1 = (const float*)d_in[15];
    const float* ker_b1 = (const float*)d_in[16];
    const float* ker_w2 = (const float*)d_in[17];
    const float* ker_b2 = (const float*)d_in[18];
    const float* root   = (const float*)d_in[19];
    const float* gbias  = (const float*)d_in[20];
    float* out = (float*)d_out;

    char* ws = (char*)d_ws;
    size_t off = 0;
    auto alloc = [&](size_t bytes) {
        void* p = ws + off;
        off += (bytes + 255) & ~(size_t)255;
        return p;
    };
    float* xn   = (float*)alloc(524288 * 4);
    float* agg  = (float*)alloc(524288 * 4);
    float* osum = (float*)alloc(524288 * 4);
    float* Gre  = (float*)alloc(131072 * 4);
    float* Gim  = (float*)alloc(131072 * 4);
    float* Yr   = (float*)alloc(65536 * 4);
    float* Yi   = (float*)alloc(65536 * 4);
    _Float16* whi = (_Float16*)alloc(65536 * 2);
    _Float16* wlo = (_Float16*)alloc(65536 * 2);

    k_pre<<<384, 256, 0, stream>>>(nodes, ker_w2, wm_w1, wm_b1, wm_w2, wm_b2,
                                   xn, agg, osum, Gre, Gim, whi, wlo);
    k_g1<<<1280, 256, 0, stream>>>(Gre, Gim, w1re, w1im, w2re, w2im, Yr, Yi,
                                   eattr, ker_w1, ker_b1, ker_b2, whi, wlo, xn, eidx, agg);
    k_g2<<<1152, 256, 0, stream>>>(Yr, Yi, mlp_w1, mlp_b1, mlp_w2, mlp_b2, osum,
                                   eattr, ker_w1, ker_b1, ker_b2, whi, wlo, xn, eidx, agg);
    k_final<<<1024, 256, 0, stream>>>(osum, agg, xn, root, gbias, out);
}

// Round 10
// 247.302 us; speedup vs baseline: 1.0358x; 1.0286x over previous
//
#include <hip/hip_runtime.h>

#define E_ 131072

typedef _Float16 half8 __attribute__((ext_vector_type(8)));
typedef float f32x4 __attribute__((ext_vector_type(4)));

__device__ __forceinline__ float gelu_f(float x) {
    return 0.5f * x * (1.0f + erff(x * 0.70710678118654752f));
}

#define TWOPI_64 (6.2831853071795864769f / 64.0f)

__device__ __forceinline__ void block_reduce2(float& s, float& s2, float* red) {
    #pragma unroll
    for (int off = 32; off > 0; off >>= 1) {
        s  += __shfl_down(s, off, 64);
        s2 += __shfl_down(s2, off, 64);
    }
    int lane = threadIdx.x & 63, wv = threadIdx.x >> 6;
    __syncthreads();
    if (lane == 0) { red[wv] = s; red[wv + 4] = s2; }
    __syncthreads();
    s  = red[0] + red[1] + red[2] + red[3];
    s2 = red[4] + red[5] + red[6] + red[7];
}

// ---- GNO 64-edge chunk body (verified R6/R8/R9 code path, untouched) ----
__device__ __forceinline__ void gno_body(int e0, float* sbufF, float* sB2, int* ssrc, int* sdst,
                                         const float* __restrict__ ea,
                                         const float* __restrict__ kw1, const float* __restrict__ kb1,
                                         const float* __restrict__ kb2,
                                         const _Float16* __restrict__ whi, const _Float16* __restrict__ wlo,
                                         const float* __restrict__ xn, const int* __restrict__ ei,
                                         float* __restrict__ agg) {
    _Float16* sxTh = (_Float16*)sbufF;
    int t = threadIdx.x;
    int lane = t & 63, wv = t >> 6, quad = lane >> 4, l15 = lane & 15;
    int eg = wv >> 1, t2 = wv & 1;

    if (t < 64) ssrc[t] = ei[e0 + t];
    else if (t < 128) sdst[t - 64] = ei[E_ + e0 + t - 64];
    for (int f = t; f < 1024; f += 256) sB2[f] = kb2[f];
    {
        int r = t >> 2, k0 = (t & 3) * 16;
        const float* ep = ea + (e0 + r) * 6;
        float e6[6];
        #pragma unroll
        for (int d = 0; d < 6; ++d) e6[d] = ep[d];
        #pragma unroll
        for (int kk = 0; kk < 16; ++kk) {
            int k = k0 + kk;
            float acc = kb1[k];
            #pragma unroll
            for (int d = 0; d < 6; ++d) acc += e6[d] * kw1[d * 64 + k];
            sbufF[r * 68 + k] = gelu_f(acc);
        }
    }
    __syncthreads();
    half8 ahi[2][2], alo[2][2];
    #pragma unroll
    for (int et = 0; et < 2; ++et) {
        #pragma unroll
        for (int kh = 0; kh < 2; ++kh) {
            const float* hp = sbufF + (eg * 32 + et * 16 + l15) * 68 + kh * 32 + quad * 8;
            float4 h0 = *(const float4*)hp;
            float4 h1 = *(const float4*)(hp + 4);
            float hv[8] = {h0.x, h0.y, h0.z, h0.w, h1.x, h1.y, h1.z, h1.w};
            half8 hh, hl;
            #pragma unroll
            for (int j = 0; j < 8; ++j) {
                _Float16 hi = (_Float16)hv[j];
                hh[j] = hi;
                hl[j] = (_Float16)(hv[j] - (float)hi);
            }
            ahi[et][kh] = hh;
            alo[et][kh] = hl;
        }
    }
    __syncthreads();
    {
        int b = t & 3, r = t >> 2;
        int s = ssrc[r];
        int pe = (r >> 5) * 32 + ((r >> 2) & 3) * 8 + ((r >> 4) & 1) * 4 + (r & 3);
        const float4* xp = (const float4*)(xn + (b * 4096 + s) * 32);
        _Float16* dp = sxTh + b * 2312 + pe;
        #pragma unroll
        for (int q = 0; q < 8; ++q) {
            float4 v = xp[q];
            dp[(q * 4 + 0) * 72] = (_Float16)v.x;
            dp[(q * 4 + 1) * 72] = (_Float16)v.y;
            dp[(q * 4 + 2) * 72] = (_Float16)v.z;
            dp[(q * 4 + 3) * 72] = (_Float16)v.w;
        }
    }
    __syncthreads();
    float msg[4][2][4];
    #pragma unroll
    for (int b = 0; b < 4; ++b)
        #pragma unroll
        for (int et = 0; et < 2; ++et)
            #pragma unroll
            for (int r = 0; r < 4; ++r) msg[b][et][r] = 0.f;

    for (int i = 0; i < 32; ++i) {
        float b2v = sB2[i * 32 + t2 * 16 + l15];
        int f0 = (i * 4 + t2 * 2) * 512 + lane * 8;
        half8 bhi0 = *(const half8*)(whi + f0);
        half8 bhi1 = *(const half8*)(whi + f0 + 512);
        half8 blo0 = *(const half8*)(wlo + f0);
        half8 blo1 = *(const half8*)(wlo + f0 + 512);
        f32x4 acc[2];
        #pragma unroll
        for (int et = 0; et < 2; ++et) {
            f32x4 ac = {b2v, b2v, b2v, b2v};
            ac = __builtin_amdgcn_mfma_f32_16x16x32_f16(ahi[et][0], bhi0, ac, 0, 0, 0);
            ac = __builtin_amdgcn_mfma_f32_16x16x32_f16(ahi[et][1], bhi1, ac, 0, 0, 0);
            ac = __builtin_amdgcn_mfma_f32_16x16x32_f16(ahi[et][0], blo0, ac, 0, 0, 0);
            ac = __builtin_amdgcn_mfma_f32_16x16x32_f16(ahi[et][1], blo1, ac, 0, 0, 0);
            ac = __builtin_amdgcn_mfma_f32_16x16x32_f16(alo[et][0], bhi0, ac, 0, 0, 0);
            ac = __builtin_amdgcn_mfma_f32_16x16x32_f16(alo[et][1], bhi1, ac, 0, 0, 0);
            acc[et] = ac;
        }
        #pragma unroll
        for (int b = 0; b < 4; ++b) {
            const half8 xv = *(const half8*)(sxTh + b * 2312 + i * 72 + eg * 32 + quad * 8);
            #pragma unroll
            for (int et = 0; et < 2; ++et) {
                msg[b][et][0] += (float)xv[et * 4 + 0] * acc[et][0];
                msg[b][et][1] += (float)xv[et * 4 + 1] * acc[et][1];
                msg[b][et][2] += (float)xv[et * 4 + 2] * acc[et][2];
                msg[b][et][3] += (float)xv[et * 4 + 3] * acc[et][3];
            }
        }
    }
    int o = t2 * 16 + l15;
    #pragma unroll
    for (int et = 0; et < 2; ++et) {
        #pragma unroll
        for (int r = 0; r < 4; ++r) {
            int row = eg * 32 + et * 16 + quad * 4 + r;
            int d = sdst[row];
            #pragma unroll
            for (int b = 0; b < 4; ++b) {
                atomicAdd(&agg[(b * 4096 + d) * 32 + o], msg[b][et][r]);
            }
        }
    }
}

// ---------------- L1 (lean): IN + DFT1 + agg-zero | w2 repack ----------------
__global__ __launch_bounds__(256, 4) void k_pre(const float* __restrict__ nodes,
                                                const float* __restrict__ w2,
                                                float* __restrict__ xn,
                                                float* __restrict__ agg,
                                                float* __restrict__ Gre, float* __restrict__ Gim,
                                                _Float16* __restrict__ whi, _Float16* __restrict__ wlo) {
    int t = threadIdx.x;
    if (blockIdx.x >= 256) {
        int g0 = (blockIdx.x - 256) * 512 + t;
        #pragma unroll 1
        for (int rep = 0; rep < 2; ++rep) {
            int g = g0 + rep * 256;
            int j = g & 7, l = (g >> 3) & 63, fid = g >> 9;
            int i = fid >> 2, t2 = (fid >> 1) & 1, kh = fid & 1;
            int quad = l >> 4, l15 = l & 15;
            int k = kh * 32 + quad * 8 + j;
            int n = i * 32 + t2 * 16 + l15;
            float v = w2[k * 1024 + n];
            _Float16 hi = (_Float16)v;
            whi[g] = hi;
            wlo[g] = (_Float16)(v - (float)hi);
        }
        return;
    }
    int bh = blockIdx.x;
    __shared__ float sx[2048];
    __shared__ float tc[64], ts[64];
    __shared__ float red[8];
    const float4* src = (const float4*)(nodes + bh * 2048);
    float4* dst = (float4*)(xn + bh * 2048);
    float4* az = (float4*)(agg + bh * 2048);
    if (t < 64) { float a = TWOPI_64 * t; tc[t] = cosf(a); ts[t] = sinf(a); }
    float4 v0 = src[t * 2], v1 = src[t * 2 + 1];
    float s  = v0.x + v0.y + v0.z + v0.w + v1.x + v1.y + v1.z + v1.w;
    float s2 = v0.x*v0.x + v0.y*v0.y + v0.z*v0.z + v0.w*v0.w
             + v1.x*v1.x + v1.y*v1.y + v1.z*v1.z + v1.w*v1.w;
    block_reduce2(s, s2, red);
    float mean = s * (1.0f / 2048.0f);
    float var  = s2 * (1.0f / 2048.0f) - mean * mean;
    float sc = rsqrtf(var + 1e-5f);
    v0.x = (v0.x - mean) * sc; v0.y = (v0.y - mean) * sc;
    v0.z = (v0.z - mean) * sc; v0.w = (v0.w - mean) * sc;
    v1.x = (v1.x - mean) * sc; v1.y = (v1.y - mean) * sc;
    v1.z = (v1.z - mean) * sc; v1.w = (v1.w - mean) * sc;
    dst[t * 2] = v0; dst[t * 2 + 1] = v1;
    float4 z = {0.f, 0.f, 0.f, 0.f};
    az[t * 2] = z; az[t * 2 + 1] = z;
    ((float4*)sx)[t * 2] = v0;
    ((float4*)sx)[t * 2 + 1] = v1;
    __syncthreads();
    #pragma unroll 1
    for (int rep = 0; rep < 2; ++rep) {
        int oi = rep * 256 + t;
        int ky = oi >> 5, i = oi & 31;
        float re = 0.f, im = 0.f;
        #pragma unroll 8
        for (int w = 0; w < 64; ++w) {
            float v = sx[w * 32 + i];
            int m = (ky * w) & 63;
            re += v * tc[m];
            im -= v * ts[m];
        }
        Gre[bh * 512 + oi] = re;
        Gim[bh * 512 + oi] = im;
    }
}

// ---------------- L2: 0..127 fxy | 128..383 x2 -> osum | 384..1407 GNO chunks 0..1023 ----------------
__global__ __launch_bounds__(256, 4) void k_g1(
        const float* __restrict__ Gre, const float* __restrict__ Gim,
        const float* __restrict__ w1re, const float* __restrict__ w1im,
        const float* __restrict__ w2re, const float* __restrict__ w2im,
        float* __restrict__ Yr, float* __restrict__ Yi,
        const float* __restrict__ ww1, const float* __restrict__ wb1,
        const float* __restrict__ ww2, const float* __restrict__ wb2,
        float* __restrict__ osum,
        const float* __restrict__ ea,
        const float* __restrict__ kw1, const float* __restrict__ kb1,
        const float* __restrict__ kb2,
        const _Float16* __restrict__ whi, const _Float16* __restrict__ wlo,
        const float* __restrict__ xn,
        const int* __restrict__ ei,
        float* __restrict__ agg) {
    __shared__ __align__(16) float U[5648];
    __shared__ int ssrc[64], sdst[64];
    int t = threadIdx.x;

    if (blockIdx.x < 128) {
        // ---- fxy ----
        float* tc  = U;
        float* ts  = U + 64;
        float* sXr = U + 128;
        float* sXi = U + 656;
        int bid = blockIdx.x;
        int b = bid >> 5, kxi = bid & 31;
        int kx = kxi + (kxi < 16 ? 0 : 32);
        int x = kxi & 15;
        const float* wre = (kxi < 16) ? w1re : w2re;
        const float* wim = (kxi < 16) ? w1im : w2im;
        if (t < 64) { float a = TWOPI_64 * t; tc[t] = cosf(a); ts[t] = sinf(a); }
        __syncthreads();
        #pragma unroll 1
        for (int rep = 0; rep < 2; ++rep) {
            int oi = rep * 256 + t;
            int ky = oi >> 5, i = oi & 31;
            float re = 0.f, im = 0.f;
            #pragma unroll 8
            for (int h = 0; h < 64; ++h) {
                int gidx = (b * 64 + h) * 512 + ky * 32 + i;
                float gr = Gre[gidx], gi = Gim[gidx];
                int m = (kx * h) & 63;
                float c = tc[m], sv = ts[m];
                re += gr * c + gi * sv;
                im += gi * c - gr * sv;
            }
            sXr[ky * 33 + i] = re;
            sXi[ky * 33 + i] = im;
        }
        __syncthreads();
        #pragma unroll 1
        for (int rep = 0; rep < 2; ++rep) {
            int oi = rep * 256 + t;
            int ky = oi & 15, o = oi >> 4;
            float re = 0.f, im = 0.f;
            #pragma unroll 4
            for (int i = 0; i < 32; ++i) {
                float xr = sXr[ky * 33 + i], xi = sXi[ky * 33 + i];
                int widx = (i * 32 + o) * 256 + x * 16 + ky;
                float wr = wre[widx], wi = wim[widx];
                re += xr * wr - xi * wi;
                im += xr * wi + xi * wr;
            }
            Yr[bid * 512 + ky * 32 + o] = re;
            Yi[bid * 512 + ky * 32 + o] = im;
        }
        return;
    }
    if (blockIdx.x < 384) {
        // ---- x2 = IN(MLP(xn)) -> osum; weights from global, hidden in f16 ----
        int bh = blockIdx.x - 128;
        float* red = U;
        float* sX = U + 8;                      // 2112
        _Float16* sHh = (_Float16*)(U + 2120);  // 64*72 halves
        for (int f = t; f < 2048; f += 256) sX[(f >> 5) * 33 + (f & 31)] = xn[bh * 2048 + f];
        __syncthreads();
        #pragma unroll 1
        for (int rep = 0; rep < 16; ++rep) {
            int idx = rep * 256 + t;
            int w = idx >> 6, k = idx & 63;
            float acc = wb1[k];
            #pragma unroll 4
            for (int c = 0; c < 32; ++c) acc += sX[w * 33 + c] * ww1[c * 64 + k];
            sHh[w * 72 + k] = (_Float16)gelu_f(acc);
        }
        __syncthreads();
        float s = 0.f, s2 = 0.f;
        #pragma unroll 1
        for (int rep = 0; rep < 8; ++rep) {
            int idx = rep * 256 + t;
            int w = idx >> 5, o = idx & 31;
            float acc = wb2[o];
            #pragma unroll 4
            for (int k = 0; k < 64; ++k) acc += (float)sHh[w * 72 + k] * ww2[k * 32 + o];
            sX[w * 33 + o] = acc;
            s += acc; s2 += acc * acc;
        }
        block_reduce2(s, s2, red);
        float mean = s * (1.0f / 2048.0f);
        float sc = rsqrtf(s2 * (1.0f / 2048.0f) - mean * mean + 1e-5f);
        #pragma unroll 1
        for (int rep = 0; rep < 8; ++rep) {
            int idx = rep * 256 + t;
            int w = idx >> 5, o = idx & 31;
            osum[bh * 2048 + idx] = (sX[w * 33 + o] - mean) * sc;
        }
        return;
    }
    gno_body((blockIdx.x - 384) * 64, U, U + 4624, ssrc, sdst,
             ea, kw1, kb1, kb2, whi, wlo, xn, ei, agg);
}

// ---------------- L3: 0..255 zx1 (osum += x1) | 256..1279 GNO chunks 1024..2047 ----------------
__global__ __launch_bounds__(256, 4) void k_g2(
        const float* __restrict__ Yr, const float* __restrict__ Yi,
        const float* __restrict__ mw1, const float* __restrict__ mb1,
        const float* __restrict__ mw2, const float* __restrict__ mb2,
        float* __restrict__ osum,
        const float* __restrict__ ea,
        const float* __restrict__ kw1, const float* __restrict__ kb1,
        const float* __restrict__ kb2,
        const _Float16* __restrict__ whi, const _Float16* __restrict__ wlo,
        const float* __restrict__ xn,
        const int* __restrict__ ei,
        float* __restrict__ agg) {
    __shared__ __align__(16) float U[5648];
    __shared__ int ssrc[64], sdst[64];
    int t = threadIdx.x;

    if (blockIdx.x < 256) {
        // ---- zx1: Z + irfft + IN + MLP -> osum += x1; weights global, hidden f16 ----
        int bh = blockIdx.x;
        int b = bh >> 6, h = bh & 63;
        float* tc  = U;                          // 64
        float* ts  = U + 64;                     // 64
        float* red = U + 128;                    // 8
        float* sZr = U + 136;                    // 528
        float* sZi = U + 664;                    // 528
        float* sP  = U + 1192;                   // 2112
        _Float16* sHh = (_Float16*)(U + 3304);   // 64*72 halves = 2304 floats
        if (t < 64) { float a = TWOPI_64 * t; tc[t] = cosf(a); ts[t] = sinf(a); }
        __syncthreads();
        #pragma unroll 1
        for (int rep = 0; rep < 2; ++rep) {
            int oi = rep * 256 + t;
            int ky = oi >> 5, o = oi & 31;
            float re = 0.f, im = 0.f;
            #pragma unroll 4
            for (int kxi = 0; kxi < 32; ++kxi) {
                int kx = kxi + (kxi < 16 ? 0 : 32);
                int m = (kx * h) & 63;
                float c = tc[m], sv = ts[m];
                int yidx = (b * 32 + kxi) * 512 + ky * 32 + o;
                float yr = Yr[yidx], yi = Yi[yidx];
                re += yr * c - yi * sv;
                im += yr * sv + yi * c;
            }
            sZr[ky * 33 + o] = re;
            sZi[ky * 33 + o] = im;
        }
        __syncthreads();
        float s = 0.f, s2 = 0.f;
        #pragma unroll 1
        for (int rep = 0; rep < 8; ++rep) {
            int idx = rep * 256 + t;
            int w = idx >> 5, o = idx & 31;
            float acc = sZr[o];  // ky=0: real part only (irfft drops imag of DC bin)
            #pragma unroll
            for (int ky = 1; ky < 16; ++ky) {
                int m = (ky * w) & 63;
                acc += 2.0f * (sZr[ky * 33 + o] * tc[m] - sZi[ky * 33 + o] * ts[m]);
            }
            acc *= (1.0f / 4096.0f);
            sP[w * 33 + o] = acc;
            s += acc; s2 += acc * acc;
        }
        block_reduce2(s, s2, red);
        float mean = s * (1.0f / 2048.0f);
        float sc = rsqrtf(s2 * (1.0f / 2048.0f) - mean * mean + 1e-5f);
        #pragma unroll 1
        for (int rep = 0; rep < 8; ++rep) {
            int idx = rep * 256 + t;
            int w = idx >> 5, o = idx & 31;
            sP[w * 33 + o] = (sP[w * 33 + o] - mean) * sc;
        }
        __syncthreads();
        #pragma unroll 1
        for (int rep = 0; rep < 16; ++rep) {
            int idx = rep * 256 + t;
            int w = idx >> 6, k = idx & 63;
            float acc = mb1[k];
            #pragma unroll 4
            for (int c = 0; c < 32; ++c) acc += sP[w * 33 + c] * mw1[c * 64 + k];
            sHh[w * 72 + k] = (_Float16)gelu_f(acc);
        }
        __syncthreads();
        #pragma unroll 1
        for (int rep = 0; rep < 8; ++rep) {
            int idx = rep * 256 + t;
            int w = idx >> 5, o = idx & 31;
            float acc = mb2[o];
            #pragma unroll 4
            for (int k = 0; k < 64; ++k) acc += (float)sHh[w * 72 + k] * mw2[k * 32 + o];
            osum[bh * 2048 + idx] += acc;
        }
        return;
    }
    gno_body((1024 + blockIdx.x - 256) * 64, U, U + 4624, ssrc, sdst,
             ea, kw1, kb1, kb2, whi, wlo, xn, ei, agg);
}

// ---------------- L4: out = gelu(osum + agg + xn@root + gbias), quarter-planes ----------------
__global__ __launch_bounds__(256, 4) void k_final(const float* __restrict__ osum, const float* __restrict__ agg,
                                                  const float* __restrict__ xn, const float* __restrict__ root,
                                                  const float* __restrict__ gbias, float* __restrict__ out) {
    int bh = blockIdx.x >> 2, q = blockIdx.x & 3;
    int base = bh * 2048 + q * 512;
    int t = threadIdx.x;
    __shared__ float sX[16 * 33];
    __shared__ float sR[1024];
    for (int f = t; f < 512; f += 256) sX[(f >> 5) * 33 + (f & 31)] = xn[base + f];
    for (int f = t; f < 1024; f += 256) sR[f] = root[f];
    __syncthreads();
    #pragma unroll 1
    for (int rep = 0; rep < 2; ++rep) {
        int idx = rep * 256 + t;
        int w = idx >> 5, o = idx & 31;
        float acc = gbias[o] + osum[base + idx] + agg[base + idx];
        #pragma unroll 4
        for (int c = 0; c < 32; ++c) acc += sX[w * 33 + c] * sR[c * 32 + o];
        out[base + idx] = gelu_f(acc);
    }
}

extern "C" void kernel_launch(void* const* d_in, const int* in_sizes, int n_in,
                              void* d_out, int out_size, void* d_ws, size_t ws_size,
                              hipStream_t stream) {
    (void)in_sizes; (void)n_in; (void)out_size; (void)ws_size;
    const float* nodes  = (const float*)d_in[0];
    const int*   eidx   = (const int*)d_in[1];
    const float* eattr  = (const float*)d_in[2];
    const float* w1re   = (const float*)d_in[3];
    const float* w1im   = (const float*)d_in[4];
    const float* w2re   = (const float*)d_in[5];
    const float* w2im   = (const float*)d_in[6];
    const float* mlp_w1 = (const float*)d_in[7];
    const float* mlp_b1 = (const float*)d_in[8];
    const float* mlp_w2 = (const float*)d_in[9];
    const float* mlp_b2 = (const float*)d_in[10];
    const float* wm_w1  = (const float*)d_in[11];
    const float* wm_b1  = (const float*)d_in[12];
    const float* wm_w2  = (const float*)d_in[13];
    const float* wm_b2  = (const float*)d_in[14];
    const float* ker_w1 = (const float*)d_in[15];
    const float* ker_b1 = (const float*)d_in[16];
    const float* ker_w2 = (const float*)d_in[17];
    const float* ker_b2 = (const float*)d_in[18];
    const float* root   = (const float*)d_in[19];
    const float* gbias  = (const float*)d_in[20];
    float* out = (float*)d_out;

    char* ws = (char*)d_ws;
    size_t off = 0;
    auto alloc = [&](size_t bytes) {
        void* p = ws + off;
        off += (bytes + 255) & ~(size_t)255;
        return p;
    };
    float* xn   = (float*)alloc(524288 * 4);
    float* agg  = (float*)alloc(524288 * 4);
    float* osum = (float*)alloc(524288 * 4);
    float* Gre  = (float*)alloc(131072 * 4);
    float* Gim  = (float*)alloc(131072 * 4);
    float* Yr   = (float*)alloc(65536 * 4);
    float* Yi   = (float*)alloc(65536 * 4);
    _Float16* whi = (_Float16*)alloc(65536 * 2);
    _Float16* wlo = (_Float16*)alloc(65536 * 2);

    k_pre<<<384, 256, 0, stream>>>(nodes, ker_w2, xn, agg, Gre, Gim, whi, wlo);
    k_g1<<<1408, 256, 0, stream>>>(Gre, Gim, w1re, w1im, w2re, w2im, Yr, Yi,
                                   wm_w1, wm_b1, wm_w2, wm_b2, osum,
                                   eattr, ker_w1, ker_b1, ker_b2, whi, wlo, xn, eidx, agg);
    k_g2<<<1280, 256, 0, stream>>>(Yr, Yi, mlp_w1, mlp_b1, mlp_w2, mlp_b2, osum,
                                   eattr, ker_w1, ker_b1, ker_b2, whi, wlo, xn, eidx, agg);
    k_final<<<1024, 256, 0, stream>>>(osum, agg, xn, root, gbias, out);
}